// Round 2
// baseline (195.080 us; speedup 1.0000x reference)
//
#include <hip/hip_runtime.h>

#define HW 32
#define NPIX 1024      // 32*32
#define IMG 3072       // 3*32*32

typedef float vf4 __attribute__((ext_vector_type(4)));

// ---------------- threefry2x32 (exact JAX semantics) ----------------
__device__ __forceinline__ unsigned rotl32(unsigned x, int d) {
    return (x << d) | (x >> (32 - d));
}

struct UPair { unsigned a, b; };

__device__ __forceinline__ UPair threefry2x32(unsigned k0, unsigned k1,
                                              unsigned x0, unsigned x1) {
    unsigned k2 = k0 ^ k1 ^ 0x1BD11BDAu;
    x0 += k0; x1 += k1;
#define RND(r) { x0 += x1; x1 = rotl32(x1, (r)); x1 ^= x0; }
    RND(13) RND(15) RND(26) RND(6)
    x0 += k1; x1 += k2 + 1u;
    RND(17) RND(29) RND(16) RND(24)
    x0 += k2; x1 += k0 + 2u;
    RND(13) RND(15) RND(26) RND(6)
    x0 += k0; x1 += k1 + 3u;
    RND(17) RND(29) RND(16) RND(24)
    x0 += k1; x1 += k2 + 4u;
    RND(13) RND(15) RND(26) RND(6)
    x0 += k2; x1 += k0 + 5u;
#undef RND
    return {x0, x1};
}

__device__ __forceinline__ float bits_to_u01(unsigned bits) {
    return __uint_as_float((bits >> 9) | 0x3f800000u) - 1.0f;
}

// reference _reflect with lo=-0.5, span=32 — fmod-free (exact for pow-2 span)
__device__ __forceinline__ float reflect32(float c) {
    float t = fabsf(c + 0.5f);
    float flips = floorf(t * 0.03125f);
    float extra = fmaf(flips, -32.0f, t);
    float o = (((int)flips) & 1) ? (31.5f - extra) : (extra - 0.5f);
    return fminf(fmaxf(o, 0.0f), 31.0f);
}

__device__ __forceinline__ float rfl_f(float v) {
    return __uint_as_float(__builtin_amdgcn_readfirstlane(__float_as_uint(v)));
}
__device__ __forceinline__ int rfl_i(int v) {
    return __builtin_amdgcn_readfirstlane(v);
}

// One wave per image. All LDS comms are intra-wave (DS ops from one wave
// complete in order; compiler preserves order on may-alias LDS accesses),
// so NO __syncthreads anywhere and a single in-place pixel-major buffer.
__global__ __launch_bounds__(64) void aug_kernel(
    const float* __restrict__ xin, const float* __restrict__ aff,
    const int* __restrict__ apply_crop, float* __restrict__ out, int B) {
    __shared__ vf4 buf[NPIX];          // pixel-major, {c0,c1,c2,pad}
    __shared__ float s_theta[6];
    __shared__ int s_top, s_left, s_flip, s_hue, s_gray, s_blur, s_solar;
    __shared__ float s_bright, s_contr, s_sat;

    const int b = blockIdx.x;
    const int t = threadIdx.x;         // 0..63, one wave
    const bool do_crop = (apply_crop[0] != 0);

    // ---- issue global image loads early (planar, coalesced float4) ----
    const float* src = xin + (size_t)b * IMG;
    vf4 L0[4], L1[4], L2[4];
#pragma unroll
    for (int m = 0; m < 4; ++m) {
        int p = 256 * m + 4 * t;
        L0[m] = *(const vf4*)(src + p);
        L1[m] = *(const vf4*)(src + NPIX + p);
        L2[m] = *(const vf4*)(src + 2 * NPIX + p);
    }

    const size_t OUT_IMG = (size_t)B * IMG;
    if (t < 6) {  // theta into LDS + affine passthrough output
        float v = aff[b * 6 + t];
        s_theta[t] = v;
        out[OUT_IMG + (size_t)B + (size_t)b * 6 + t] = v;
    }

    // ---- per-image RNG (jax_threefry_partitionable=True semantics) ----
    if (t < 10) {
        int k = t;
        UPair K = threefry2x32(0u, 42u, 0u, (unsigned)k);  // ks[k]
        if (k < 2) {
            UPair k2 = threefry2x32(K.a, K.b, 0u, 1u);
            UPair r = threefry2x32(k2.a, k2.b, 0u, (unsigned)b);
            int val = (int)((r.a ^ r.b) & 7u);
            if (k == 0) s_top = val; else s_left = val;
        } else {
            UPair r = threefry2x32(K.a, K.b, 0u, (unsigned)b);
            float u = bits_to_u01(r.a ^ r.b);
            if      (k == 2) s_flip  = (u < 0.5f);
            else if (k == 3) s_bright = 1.0f + (u - 0.5f) * 0.8f;
            else if (k == 4) s_contr  = 1.0f + (u - 0.5f) * 0.8f;
            else if (k == 5) s_sat    = 1.0f + (u - 0.5f) * 0.8f;
            else if (k == 6) s_hue   = (u < 0.5f);
            else if (k == 7) s_gray  = (u < 0.2f);
            else if (k == 8) s_blur  = (u < 0.5f);
            else             s_solar = (u < 0.1f);
        }
    }

    // ---- denormalize + transpose to pixel-major LDS (ds_write_b128) ----
#pragma unroll
    for (int m = 0; m < 4; ++m) {
        int p = 256 * m + 4 * t;
#pragma unroll
        for (int j = 0; j < 4; ++j) {
            vf4 v;
            v.x = fmaf(L0[m][j], 0.2675f, 0.5071f);
            v.y = fmaf(L1[m][j], 0.2565f, 0.4867f);
            v.z = fmaf(L2[m][j], 0.2761f, 0.4408f);
            v.w = 0.0f;
            buf[p + j] = v;
        }
    }

    // flag/uniform broadcast (LDS reads ordered after the t<10 writes in-wave)
    if (t == 0) out[OUT_IMG + b] = s_flip ? 1.0f : 0.0f;
    const int top  = rfl_i(s_top),  left = rfl_i(s_left);
    const int flip = rfl_i(s_flip), hue  = rfl_i(s_hue);
    const int gray = rfl_i(s_gray), blur = rfl_i(s_blur), solar = rfl_i(s_solar);
    const float br   = rfl_f(s_bright);
    const float ctsa = rfl_f(s_contr) * rfl_f(s_sat);  // contrast preserves mean
    const float th0 = rfl_f(s_theta[0]), th1 = rfl_f(s_theta[1]), th2 = rfl_f(s_theta[2]);
    const float th3 = rfl_f(s_theta[3]), th4 = rfl_f(s_theta[4]), th5 = rfl_f(s_theta[5]);

    float cx[16], cy[16], cz[16];      // per-thread pixel values (3 ch)

    // ---- crop-resize, in place: read ALL taps (regs) then write back ----
    if (do_crop) {
#pragma unroll
        for (int m = 0; m < 4; ++m) {
#pragma unroll
            for (int j = 0; j < 4; ++j) {
                const int i = 4 * m + j;
                int p = 256 * m + 4 * t + j;
                int yi = p >> 5, xj = p & 31;
                // (k+0.5)*25/32-0.5 == fma(k, .78125, -.109375), exact fp32
                float dy = fmaxf(fmaf((float)yi, 0.78125f, -0.109375f), 0.0f);
                int i0 = (int)dy; float ly = dy - (float)i0; int i1 = min(i0 + 1, 24);
                float dx = fmaxf(fmaf((float)xj, 0.78125f, -0.109375f), 0.0f);
                int q0 = (int)dx; float lx = dx - (float)q0; int q1 = min(q0 + 1, 24);
                int r0 = (top + i0) << 5, r1 = (top + i1) << 5;
                int c0 = left + q0, c1 = left + q1;
                float omy = 1.0f - ly, omx = 1.0f - lx;
                float w00 = omy * omx, w01 = omy * lx;
                float w10 = ly * omx, w11 = ly * lx;
                vf4 t00 = buf[r0 + c0], t01 = buf[r0 + c1];
                vf4 t10 = buf[r1 + c0], t11 = buf[r1 + c1];
                cx[i] = fmaf(t00.x, w00, fmaf(t01.x, w01, fmaf(t10.x, w10, t11.x * w11)));
                cy[i] = fmaf(t00.y, w00, fmaf(t01.y, w01, fmaf(t10.y, w10, t11.y * w11)));
                cz[i] = fmaf(t00.z, w00, fmaf(t01.z, w01, fmaf(t10.z, w10, t11.z * w11)));
            }
        }
#pragma unroll
        for (int m = 0; m < 4; ++m) {
#pragma unroll
            for (int j = 0; j < 4; ++j) {
                const int i = 4 * m + j;
                int p = 256 * m + 4 * t + j;
                vf4 v; v.x = cx[i]; v.y = cy[i]; v.z = cz[i]; v.w = 0.0f;
                buf[p] = v;
            }
        }
    }

    // ---- grid sample (flip folded) + fused color chain, results in regs ----
#pragma unroll
    for (int m = 0; m < 4; ++m) {
#pragma unroll
        for (int j = 0; j < 4; ++j) {
            const int i = 4 * m + j;
            int p = 256 * m + 4 * t + j;
            int yi = p >> 5, xj = p & 31;
            float xn = (float)xj * 0.0625f - 0.96875f;
            float yn = (float)yi * 0.0625f - 0.96875f;
            float gx = fmaf(th0, xn, fmaf(th1, yn, th2));
            float gy = fmaf(th3, xn, fmaf(th4, yn, th5));
            float ix = reflect32(fmaf(gx, 16.0f, 15.5f));
            float iy = reflect32(fmaf(gy, 16.0f, 15.5f));
            float fy = floorf(iy), fx = floorf(ix);
            float wy = iy - fy, wx = ix - fx;
            int y0 = (int)fy; int y1 = min(y0 + 1, 31);
            int x0 = (int)fx; int x1 = min(x0 + 1, 31);
            if (flip) { x0 = 31 - x0; x1 = 31 - x1; }
            int r0 = y0 << 5, r1 = y1 << 5;
            float omy = 1.0f - wy, omx = 1.0f - wx;
            float w00 = omy * omx, w01 = omy * wx;
            float w10 = wy * omx, w11 = wy * wx;
            vf4 t00 = buf[r0 + x0], t01 = buf[r0 + x1];
            vf4 t10 = buf[r1 + x0], t11 = buf[r1 + x1];
            float ch0 = fmaf(t00.x, w00, fmaf(t01.x, w01, fmaf(t10.x, w10, t11.x * w11)));
            float ch1 = fmaf(t00.y, w00, fmaf(t01.y, w01, fmaf(t10.y, w10, t11.y * w11)));
            float ch2 = fmaf(t00.z, w00, fmaf(t01.z, w01, fmaf(t10.z, w10, t11.z * w11)));
            ch0 *= br; ch1 *= br; ch2 *= br;
            float g = (ch0 + ch1 + ch2) * (1.0f / 3.0f);
            ch0 = fmaf(ch0 - g, ctsa, g);
            ch1 = fmaf(ch1 - g, ctsa, g);
            ch2 = fmaf(ch2 - g, ctsa, g);
            if (hue) { float tmp = ch0; ch0 = ch2; ch2 = tmp; }
            if (gray) { ch0 = ch1 = ch2 = g; }
            cx[i] = ch0; cy[i] = ch1; cz[i] = ch2;
        }
    }

    // ---- blur: H-pass in registers (shuffle edges), V-pass via LDS ----
    if (blur) {
        const int le = ((t & 7) == 0), re = ((t & 7) == 7);
        const int tl = (t - 1) & 63, tr = (t + 1) & 63;
#pragma unroll
        for (int m = 0; m < 4; ++m) {
            const int q = 4 * m;
            {   // channel 0
                float v0 = cx[q], v1 = cx[q+1], v2 = cx[q+2], v3 = cx[q+3];
                float lf = __shfl(v3, tl), rt = __shfl(v0, tr);
                if (le) lf = v0;  if (re) rt = v3;
                float s01 = v0 + v1, s23 = v2 + v3;
                cx[q] = lf + s01; cx[q+1] = s01 + v2; cx[q+2] = v1 + s23; cx[q+3] = s23 + rt;
            }
            {   // channel 1
                float v0 = cy[q], v1 = cy[q+1], v2 = cy[q+2], v3 = cy[q+3];
                float lf = __shfl(v3, tl), rt = __shfl(v0, tr);
                if (le) lf = v0;  if (re) rt = v3;
                float s01 = v0 + v1, s23 = v2 + v3;
                cy[q] = lf + s01; cy[q+1] = s01 + v2; cy[q+2] = v1 + s23; cy[q+3] = s23 + rt;
            }
            {   // channel 2
                float v0 = cz[q], v1 = cz[q+1], v2 = cz[q+2], v3 = cz[q+3];
                float lf = __shfl(v3, tl), rt = __shfl(v0, tr);
                if (le) lf = v0;  if (re) rt = v3;
                float s01 = v0 + v1, s23 = v2 + v3;
                cz[q] = lf + s01; cz[q+1] = s01 + v2; cz[q+2] = v1 + s23; cz[q+3] = s23 + rt;
            }
        }
        // write H rows (in place; sample reads are all done)
#pragma unroll
        for (int m = 0; m < 4; ++m) {
#pragma unroll
            for (int j = 0; j < 4; ++j) {
                const int i = 4 * m + j;
                int p = 256 * m + 4 * t + j;
                vf4 v; v.x = cx[i]; v.y = cy[i]; v.z = cz[i]; v.w = 0.0f;
                buf[p] = v;
            }
        }
        // V-pass: center H is in regs, only ±1 rows from LDS (clamped)
#pragma unroll
        for (int m = 0; m < 4; ++m) {
#pragma unroll
            for (int j = 0; j < 4; ++j) {
                const int i = 4 * m + j;
                int p = 256 * m + 4 * t + j;
                int yi = p >> 5, xj = p & 31;
                vf4 up = buf[(max(yi - 1, 0) << 5) + xj];
                vf4 dn = buf[(min(yi + 1, 31) << 5) + xj];
                cx[i] = (up.x + cx[i] + dn.x) * (1.0f / 9.0f);
                cy[i] = (up.y + cy[i] + dn.y) * (1.0f / 9.0f);
                cz[i] = (up.z + cz[i] + dn.z) * (1.0f / 9.0f);
            }
        }
    }

    // ---- solarize + clip + renorm + coalesced float4 stores (planar) ----
    {
        const float INV0 = 1.0f / 0.2675f, INV1 = 1.0f / 0.2565f, INV2 = 1.0f / 0.2761f;
        float* o = out + (size_t)b * IMG;
#pragma unroll
        for (int m = 0; m < 4; ++m) {
            int p = 256 * m + 4 * t;
            vf4 o0, o1, o2;
#pragma unroll
            for (int j = 0; j < 4; ++j) {
                const int i = 4 * m + j;
                float r0v = cx[i], r1v = cy[i], r2v = cz[i];
                if (solar) {
                    if (r0v > 0.5f) r0v = 1.0f - r0v;
                    if (r1v > 0.5f) r1v = 1.0f - r1v;
                    if (r2v > 0.5f) r2v = 1.0f - r2v;
                }
                r0v = fminf(fmaxf(r0v, 0.0f), 1.0f);
                r1v = fminf(fmaxf(r1v, 0.0f), 1.0f);
                r2v = fminf(fmaxf(r2v, 0.0f), 1.0f);
                o0[j] = (r0v - 0.5071f) * INV0;
                o1[j] = (r1v - 0.4867f) * INV1;
                o2[j] = (r2v - 0.4408f) * INV2;
            }
            *(vf4*)(o + p) = o0;
            *(vf4*)(o + NPIX + p) = o1;
            *(vf4*)(o + 2 * NPIX + p) = o2;
        }
    }
}

extern "C" void kernel_launch(void* const* d_in, const int* in_sizes, int n_in,
                              void* d_out, int out_size, void* d_ws, size_t ws_size,
                              hipStream_t stream) {
    const float* x = (const float*)d_in[0];
    const float* aff = (const float*)d_in[1];
    const int* ac = (const int*)d_in[2];
    float* out = (float*)d_out;
    int B = in_sizes[0] / IMG;
    aug_kernel<<<dim3(B), dim3(64), 0, stream>>>(x, aff, ac, out, B);
}

// Round 3
// 182.277 us; speedup vs baseline: 1.0702x; 1.0702x over previous
//
#include <hip/hip_runtime.h>

#define HW 32
#define NPIX 1024      // 32*32
#define IMG 3072       // 3*32*32

typedef float vf4 __attribute__((ext_vector_type(4)));

// ---------------- threefry2x32 (exact JAX semantics) ----------------
__device__ __forceinline__ unsigned rotl32(unsigned x, int d) {
    return (x << d) | (x >> (32 - d));
}

struct UPair { unsigned a, b; };

__device__ __forceinline__ UPair threefry2x32(unsigned k0, unsigned k1,
                                              unsigned x0, unsigned x1) {
    unsigned k2 = k0 ^ k1 ^ 0x1BD11BDAu;
    x0 += k0; x1 += k1;
#define RND(r) { x0 += x1; x1 = rotl32(x1, (r)); x1 ^= x0; }
    RND(13) RND(15) RND(26) RND(6)
    x0 += k1; x1 += k2 + 1u;
    RND(17) RND(29) RND(16) RND(24)
    x0 += k2; x1 += k0 + 2u;
    RND(13) RND(15) RND(26) RND(6)
    x0 += k0; x1 += k1 + 3u;
    RND(17) RND(29) RND(16) RND(24)
    x0 += k1; x1 += k2 + 4u;
    RND(13) RND(15) RND(26) RND(6)
    x0 += k2; x1 += k0 + 5u;
#undef RND
    return {x0, x1};
}

__device__ __forceinline__ float bits_to_u01(unsigned bits) {
    return __uint_as_float((bits >> 9) | 0x3f800000u) - 1.0f;
}

// reference _reflect with lo=-0.5, span=32 — fmod-free (exact for pow-2 span)
__device__ __forceinline__ float reflect32(float c) {
    float t = fabsf(c + 0.5f);
    float flips = floorf(t * 0.03125f);
    float extra = fmaf(flips, -32.0f, t);
    float o = (((int)flips) & 1) ? (31.5f - extra) : (extra - 0.5f);
    return fminf(fmaxf(o, 0.0f), 31.0f);
}

__device__ __forceinline__ float rfl_f(float v) {
    return __uint_as_float(__builtin_amdgcn_readfirstlane(__float_as_uint(v)));
}
__device__ __forceinline__ int rfl_i(int v) {
    return __builtin_amdgcn_readfirstlane(v);
}

// 256 threads / 4 waves per image. Pixel-major vf4 LDS ({c0,c1,c2,pad}).
// STRIDED ownership: thread t owns pixels p = t + 256*i  =>  x = t&31 fixed,
// rows y = (t>>5) + 8*i. Every wave-wide LDS access touches 64 consecutive
// pixels -> uniform bank residues -> conflict-free b128 (8-clock floor).
__global__ __launch_bounds__(256) void aug_kernel(
    const float* __restrict__ xin, const float* __restrict__ aff,
    const int* __restrict__ apply_crop, float* __restrict__ out, int B) {
    __shared__ vf4 buf[NPIX];
    __shared__ float s_theta[6];
    __shared__ int s_top, s_left, s_flip, s_hue, s_gray, s_blur, s_solar;
    __shared__ float s_bright, s_contr, s_sat;

    const int b = blockIdx.x;
    const int t = threadIdx.x;         // 0..255
    const int x = t & 31;              // fixed column per thread
    const int yr = t >> 5;             // row base; y_i = yr + 8*i
    const bool do_crop = (apply_crop[0] != 0);

    // ---- issue global planar loads early (lane-stride-1, coalesced) ----
    const float* src = xin + (size_t)b * IMG;
    float g0[4], g1[4], g2[4];
#pragma unroll
    for (int i = 0; i < 4; ++i) {
        int p = t + 256 * i;
        g0[i] = src[p];
        g1[i] = src[NPIX + p];
        g2[i] = src[2 * NPIX + p];
    }

    const size_t OUT_IMG = (size_t)B * IMG;
    if (t < 6) {  // theta into LDS + affine passthrough output
        float v = aff[b * 6 + t];
        s_theta[t] = v;
        out[OUT_IMG + (size_t)B + (size_t)b * 6 + t] = v;
    }

    // ---- per-image RNG (jax_threefry_partitionable=True semantics) ----
    if (t < 10) {
        int k = t;
        UPair K = threefry2x32(0u, 42u, 0u, (unsigned)k);  // ks[k]
        if (k < 2) {
            UPair k2 = threefry2x32(K.a, K.b, 0u, 1u);
            UPair r = threefry2x32(k2.a, k2.b, 0u, (unsigned)b);
            int val = (int)((r.a ^ r.b) & 7u);
            if (k == 0) s_top = val; else s_left = val;
        } else {
            UPair r = threefry2x32(K.a, K.b, 0u, (unsigned)b);
            float u = bits_to_u01(r.a ^ r.b);
            if      (k == 2) s_flip  = (u < 0.5f);
            else if (k == 3) s_bright = 1.0f + (u - 0.5f) * 0.8f;
            else if (k == 4) s_contr  = 1.0f + (u - 0.5f) * 0.8f;
            else if (k == 5) s_sat    = 1.0f + (u - 0.5f) * 0.8f;
            else if (k == 6) s_hue   = (u < 0.5f);
            else if (k == 7) s_gray  = (u < 0.2f);
            else if (k == 8) s_blur  = (u < 0.5f);
            else             s_solar = (u < 0.1f);
        }
    }

    // ---- denormalize + stage pixel-major (conflict-free b128 writes) ----
#pragma unroll
    for (int i = 0; i < 4; ++i) {
        vf4 v;
        v.x = fmaf(g0[i], 0.2675f, 0.5071f);
        v.y = fmaf(g1[i], 0.2565f, 0.4867f);
        v.z = fmaf(g2[i], 0.2761f, 0.4408f);
        v.w = 0.0f;
        buf[t + 256 * i] = v;
    }
    __syncthreads();

    if (t == 0) out[OUT_IMG + b] = s_flip ? 1.0f : 0.0f;
    const int top  = rfl_i(s_top),  left = rfl_i(s_left);
    const int flip = rfl_i(s_flip), hue  = rfl_i(s_hue);
    const int gray = rfl_i(s_gray), blur = rfl_i(s_blur), solar = rfl_i(s_solar);
    const float br   = rfl_f(s_bright);
    const float ctsa = rfl_f(s_contr) * rfl_f(s_sat);  // contrast preserves mean
    const float th0 = rfl_f(s_theta[0]), th1 = rfl_f(s_theta[1]), th2 = rfl_f(s_theta[2]);
    const float th3 = rfl_f(s_theta[3]), th4 = rfl_f(s_theta[4]), th5 = rfl_f(s_theta[5]);

    float cx[4], cy[4], cz[4];

    // ---- crop-resize: read phase (regs) | BAR | write-back ----
    if (do_crop) {
        // x-only math hoisted: one column index/fraction per thread
        float dxv = fmaxf(fmaf((float)x, 0.78125f, -0.109375f), 0.0f);
        int q0 = (int)dxv; float lx = dxv - (float)q0; int q1 = min(q0 + 1, 24);
        int c0 = left + q0, c1 = left + q1;
        float omx = 1.0f - lx;
#pragma unroll
        for (int i = 0; i < 4; ++i) {
            int yi = yr + 8 * i;
            float dy = fmaxf(fmaf((float)yi, 0.78125f, -0.109375f), 0.0f);
            int i0 = (int)dy; float ly = dy - (float)i0; int i1 = min(i0 + 1, 24);
            int r0 = (top + i0) << 5, r1 = (top + i1) << 5;
            float omy = 1.0f - ly;
            float w00 = omy * omx, w01 = omy * lx;
            float w10 = ly * omx, w11 = ly * lx;
            vf4 t00 = buf[r0 + c0], t01 = buf[r0 + c1];
            vf4 t10 = buf[r1 + c0], t11 = buf[r1 + c1];
            cx[i] = fmaf(t00.x, w00, fmaf(t01.x, w01, fmaf(t10.x, w10, t11.x * w11)));
            cy[i] = fmaf(t00.y, w00, fmaf(t01.y, w01, fmaf(t10.y, w10, t11.y * w11)));
            cz[i] = fmaf(t00.z, w00, fmaf(t01.z, w01, fmaf(t10.z, w10, t11.z * w11)));
        }
        __syncthreads();   // all reads done before in-place overwrite
#pragma unroll
        for (int i = 0; i < 4; ++i) {
            vf4 v; v.x = cx[i]; v.y = cy[i]; v.z = cz[i]; v.w = 0.0f;
            buf[t + 256 * i] = v;
        }
        __syncthreads();
    }

    // ---- grid sample (flip folded) + fused color chain (regs) ----
    {
        float xn = (float)x * 0.0625f - 0.96875f;   // hoisted
#pragma unroll
        for (int i = 0; i < 4; ++i) {
            int yi = yr + 8 * i;
            float yn = (float)yi * 0.0625f - 0.96875f;
            float gx = fmaf(th0, xn, fmaf(th1, yn, th2));
            float gy = fmaf(th3, xn, fmaf(th4, yn, th5));
            float ix = reflect32(fmaf(gx, 16.0f, 15.5f));
            float iy = reflect32(fmaf(gy, 16.0f, 15.5f));
            float fy = floorf(iy), fx = floorf(ix);
            float wy = iy - fy, wx = ix - fx;
            int y0 = (int)fy; int y1 = min(y0 + 1, 31);
            int x0 = (int)fx; int x1 = min(x0 + 1, 31);
            if (flip) { x0 = 31 - x0; x1 = 31 - x1; }
            int r0 = y0 << 5, r1 = y1 << 5;
            float omy = 1.0f - wy, omx = 1.0f - wx;
            float w00 = omy * omx, w01 = omy * wx;
            float w10 = wy * omx, w11 = wy * wx;
            vf4 t00 = buf[r0 + x0], t01 = buf[r0 + x1];
            vf4 t10 = buf[r1 + x0], t11 = buf[r1 + x1];
            float ch0 = fmaf(t00.x, w00, fmaf(t01.x, w01, fmaf(t10.x, w10, t11.x * w11)));
            float ch1 = fmaf(t00.y, w00, fmaf(t01.y, w01, fmaf(t10.y, w10, t11.y * w11)));
            float ch2 = fmaf(t00.z, w00, fmaf(t01.z, w01, fmaf(t10.z, w10, t11.z * w11)));
            ch0 *= br; ch1 *= br; ch2 *= br;
            float g = (ch0 + ch1 + ch2) * (1.0f / 3.0f);
            ch0 = fmaf(ch0 - g, ctsa, g);
            ch1 = fmaf(ch1 - g, ctsa, g);
            ch2 = fmaf(ch2 - g, ctsa, g);
            if (hue) { float tmp = ch0; ch0 = ch2; ch2 = tmp; }
            if (gray) { ch0 = ch1 = ch2 = g; }
            cx[i] = ch0; cy[i] = ch1; cz[i] = ch2;
        }
    }

    // ---- blur: H-pass via lane shuffles (x±1 = lane±1), V-pass via LDS ----
    if (blur) {
        __syncthreads();   // all sample reads done before overwrite
        const int tl = t - 1, tr = t + 1;
        float hx[4], hy[4], hz[4];
#pragma unroll
        for (int i = 0; i < 4; ++i) {
            float v, lf, rt;
            v = cx[i]; lf = __shfl(v, tl); rt = __shfl(v, tr);
            if (x == 0) lf = v;  if (x == 31) rt = v;
            hx[i] = lf + v + rt;
            v = cy[i]; lf = __shfl(v, tl); rt = __shfl(v, tr);
            if (x == 0) lf = v;  if (x == 31) rt = v;
            hy[i] = lf + v + rt;
            v = cz[i]; lf = __shfl(v, tl); rt = __shfl(v, tr);
            if (x == 0) lf = v;  if (x == 31) rt = v;
            hz[i] = lf + v + rt;
        }
#pragma unroll
        for (int i = 0; i < 4; ++i) {
            vf4 v; v.x = hx[i]; v.y = hy[i]; v.z = hz[i]; v.w = 0.0f;
            buf[t + 256 * i] = v;
        }
        __syncthreads();
#pragma unroll
        for (int i = 0; i < 4; ++i) {
            int yi = yr + 8 * i;
            vf4 up = buf[(max(yi - 1, 0) << 5) + x];
            vf4 dn = buf[(min(yi + 1, 31) << 5) + x];
            cx[i] = (up.x + hx[i] + dn.x) * (1.0f / 9.0f);
            cy[i] = (up.y + hy[i] + dn.y) * (1.0f / 9.0f);
            cz[i] = (up.z + hz[i] + dn.z) * (1.0f / 9.0f);
        }
    }

    // ---- solarize + clip + renorm + planar coalesced stores ----
    {
        const float INV0 = 1.0f / 0.2675f, INV1 = 1.0f / 0.2565f, INV2 = 1.0f / 0.2761f;
        float* o = out + (size_t)b * IMG;
#pragma unroll
        for (int i = 0; i < 4; ++i) {
            int p = t + 256 * i;
            float r0v = cx[i], r1v = cy[i], r2v = cz[i];
            if (solar) {
                if (r0v > 0.5f) r0v = 1.0f - r0v;
                if (r1v > 0.5f) r1v = 1.0f - r1v;
                if (r2v > 0.5f) r2v = 1.0f - r2v;
            }
            r0v = fminf(fmaxf(r0v, 0.0f), 1.0f);
            r1v = fminf(fmaxf(r1v, 0.0f), 1.0f);
            r2v = fminf(fmaxf(r2v, 0.0f), 1.0f);
            o[p]             = (r0v - 0.5071f) * INV0;
            o[NPIX + p]      = (r1v - 0.4867f) * INV1;
            o[2 * NPIX + p]  = (r2v - 0.4408f) * INV2;
        }
    }
}

extern "C" void kernel_launch(void* const* d_in, const int* in_sizes, int n_in,
                              void* d_out, int out_size, void* d_ws, size_t ws_size,
                              hipStream_t stream) {
    const float* x = (const float*)d_in[0];
    const float* aff = (const float*)d_in[1];
    const int* ac = (const int*)d_in[2];
    float* out = (float*)d_out;
    int B = in_sizes[0] / IMG;
    aug_kernel<<<dim3(B), dim3(256), 0, stream>>>(x, aff, ac, out, B);
}